// Round 8
// baseline (352.453 us; speedup 1.0000x reference)
//
#include <hip/hip_runtime.h>
#include <stdint.h>

#define N_NODES 50000
#define DD 256
#define SS 25

typedef unsigned short u16;
typedef __attribute__((ext_vector_type(8))) __bf16 bf16x8;
typedef __attribute__((ext_vector_type(4))) float f32x4;

__device__ __forceinline__ u16 f2bf(float f) {  // round-to-nearest-even
    union { float f; uint32_t i; } c;
    c.f = f;
    uint32_t r = c.i + 0x7fffu + ((c.i >> 16) & 1u);
    return (u16)(r >> 16);
}

// packed max of 2 non-negative bf16 (bit patterns monotone, sign bit 0 -> signed i16 max is exact)
__device__ __forceinline__ uint4 pkmax4(uint4 a, uint4 b) {
    uint4 d;
    asm("v_pk_max_i16 %0, %1, %2" : "=v"(d.x) : "v"(a.x), "v"(b.x));
    asm("v_pk_max_i16 %0, %1, %2" : "=v"(d.y) : "v"(a.y), "v"(b.y));
    asm("v_pk_max_i16 %0, %1, %2" : "=v"(d.z) : "v"(a.z), "v"(b.z));
    asm("v_pk_max_i16 %0, %1, %2" : "=v"(d.w) : "v"(a.w), "v"(b.w));
    return d;
}

__device__ __forceinline__ void gld16(void* lds, const void* g) {
    __builtin_amdgcn_global_load_lds(
        (const __attribute__((address_space(1))) uint32_t*)g,
        (__attribute__((address_space(3))) uint32_t*)lds, 16, 0, 0);
}

// ---- f32 -> bf16 elementwise (exact: grid*block*4 == n) ----
__global__ __launch_bounds__(256) void cvt_f32_bf16_k(const float4* __restrict__ in,
                                                      u16* __restrict__ out) {
    int i = blockIdx.x * 256 + threadIdx.x;
    float4 v = in[i];
    uint2 o;
    o.x = (uint32_t)f2bf(v.x) | ((uint32_t)f2bf(v.y) << 16);
    o.y = (uint32_t)f2bf(v.z) | ((uint32_t)f2bf(v.w) << 16);
    *reinterpret_cast<uint2*>(out + (size_t)i * 4) = o;
}

// ---- weight f32 [K][256] -> bf16 MFMA B-fragment layout ----
// out[((kt*16 + ct)*64 + lane)*8 + e] = W[kt*32 + (lane>>4)*8 + e][ct*16 + (lane&15)]
__global__ __launch_bounds__(256) void cvt_w_k(const float* __restrict__ W,
                                               u16* __restrict__ out, int KT) {
    int t = blockIdx.x * 256 + threadIdx.x;
    if (t >= KT * 16 * 64) return;
    int lane = t & 63;
    int ct = (t >> 6) & 15;
    int kt = t >> 10;
    int k0 = kt * 32 + (lane >> 4) * 8;
    int col = ct * 16 + (lane & 15);
    u16 r[8];
#pragma unroll
    for (int e = 0; e < 8; e++) r[e] = f2bf(W[(size_t)(k0 + e) * DD + col]);
    uint4 v;
    v.x = (uint32_t)r[0] | ((uint32_t)r[1] << 16);
    v.y = (uint32_t)r[2] | ((uint32_t)r[3] << 16);
    v.z = (uint32_t)r[4] | ((uint32_t)r[5] << 16);
    v.w = (uint32_t)r[6] | ((uint32_t)r[7] << 16);
    *reinterpret_cast<uint4*>(out + (size_t)t * 8) = v;
}

// ==== gather body (R7-proven): XCD-sliced, chunked h/agg [8][N][32] ====
__device__ __forceinline__ void gather_body(int c, int base, const u16* __restrict__ hc,
                                            const int* __restrict__ idx,
                                            u16* __restrict__ aggc, int M, int* soff) {
    const int tid = threadIdx.x;
    for (int j = tid; j < 256 * SS; j += 256) {
        int n = base + j / SS;
        if (n >= M) n = M - 1;
        soff[j] = idx[(size_t)n * SS + (j % SS)] * 32;
    }
    __syncthreads();
    const int q = tid & 3;
    const u16* slice = hc + (size_t)c * ((size_t)N_NODES * 32) + q * 8;
    u16* aslice = aggc + (size_t)c * ((size_t)N_NODES * 32) + q * 8;
#pragma unroll 1
    for (int p = 0; p < 4; ++p) {
        const int slot = p * 64 + (tid >> 2);
        const int n = base + slot;
        const int* off = &soff[slot * SS];
        uint4 v[13];
#pragma unroll
        for (int s = 0; s < 13; ++s)
            v[s] = *reinterpret_cast<const uint4*>(slice + off[s]);
        uint4 run = v[0];
#pragma unroll
        for (int s = 1; s < 13; ++s) run = pkmax4(run, v[s]);
#pragma unroll
        for (int s = 13; s < 25; ++s)
            v[s - 13] = *reinterpret_cast<const uint4*>(slice + off[s]);
#pragma unroll
        for (int s = 0; s < 12; ++s) run = pkmax4(run, v[s]);
        if (n < M)
            *reinterpret_cast<uint4*>(aslice + (size_t)n * 32) = run;
    }
}

// ==== X-half partial GEMM body: C1[M,256] = A @ Wfc_top (f32, no bias) ====
// 128x128 tile, 4 waves, dbuf LDS, global_load_lds w16 (R2-proven structure).
__device__ __forceinline__ void xpart_body(const u16* __restrict__ A1,
                                           const u16* __restrict__ Bf,
                                           float* __restrict__ C1, int M,
                                           int row_base, int ct0b, char* smem) {
    u16(*sAB)[8192] = reinterpret_cast<u16(*)[8192]>(smem);
    const int lane = threadIdx.x & 63;
    const int w = threadIdx.x >> 6;
    const int wm = w >> 1, wn = w & 1;
    const int lr = lane & 15, lk = lane >> 4;

    f32x4 acc[4][4] = {};

    auto stage = [&](int buf, int kt) {
#pragma unroll
        for (int j = 0; j < 2; ++j) {
            int row = row_base + j * 64 + lane;
            if (row >= M) row = M - 1;
            gld16(&sAB[buf][(w * 2 + j) * 512 + lane * 8],
                  A1 + (size_t)row * DD + kt * 32 + w * 8);
        }
#pragma unroll
        for (int j = 0; j < 2; ++j) {
            const int nl = w * 2 + j;
            gld16(&sAB[buf][4096 + nl * 512 + lane * 8],
                  Bf + ((size_t)(kt * 16 + ct0b + nl) * 64 + lane) * 8);
        }
    };
    auto compute = [&](int buf) {
        bf16x8 a[4], b[4];
#pragma unroll
        for (int m = 0; m < 4; m++)
            a[m] = *reinterpret_cast<const bf16x8*>(
                &sAB[buf][lk * 1024 + (wm * 64 + m * 16 + lr) * 8]);
#pragma unroll
        for (int n = 0; n < 4; n++)
            b[n] = *reinterpret_cast<const bf16x8*>(
                &sAB[buf][4096 + (wn * 4 + n) * 512 + lane * 8]);
#pragma unroll
        for (int m = 0; m < 4; m++)
#pragma unroll
            for (int n = 0; n < 4; n++)
                acc[m][n] = __builtin_amdgcn_mfma_f32_16x16x32_bf16(a[m], b[n], acc[m][n], 0, 0, 0);
    };

    stage(0, 0);
    asm volatile("s_waitcnt vmcnt(0)" ::: "memory");
    __syncthreads();
    int buf = 0;
#pragma unroll
    for (int kt = 0; kt < 7; ++kt) {
        stage(buf ^ 1, kt + 1);
        compute(buf);
        asm volatile("s_waitcnt vmcnt(0)" ::: "memory");
        __syncthreads();
        buf ^= 1;
    }
    compute(buf);

    const int col_base = ct0b * 16 + wn * 64;
#pragma unroll
    for (int n = 0; n < 4; n++) {
        const int col = col_base + n * 16 + lr;
#pragma unroll
        for (int m = 0; m < 4; m++) {
            const int r0 = row_base + wm * 64 + m * 16 + lk * 4;
#pragma unroll
            for (int e = 0; e < 4; e++) {
                const int r = r0 + e;
                if (r < M) C1[(size_t)r * DD + col] = acc[m][n][e];
            }
        }
    }
}

// ==== Union kernel: gather blocks + X-half GEMM blocks, interleaved 2:1 ====
// Groups of 8 consecutive bids (one per XCD). gidx%3<2 -> gather (c=bid&7),
// gidx%3==2 -> gemm (ge8 = (gidx/3)*8 + bid&7 flattens 391x2 tile grid).
__global__ __launch_bounds__(256) void union_k(const u16* __restrict__ X,
                                               const u16* __restrict__ hc,
                                               const int* __restrict__ idx,
                                               const u16* __restrict__ Bf,
                                               u16* __restrict__ aggc,
                                               float* __restrict__ C1, int M) {
    __shared__ __align__(16) char smem[32768];
    const int bid = blockIdx.x;
    const int gidx = bid >> 3, r3 = gidx % 3, lo = bid & 7;
    if (r3 < 2) {
        const int go = (gidx / 3) * 2 + r3;  // node group 0..195
        gather_body(lo, go * 256, hc, idx, aggc, M, (int*)smem);
    } else {
        const int ge8 = (gidx / 3) * 8 + lo;  // 0..783
        if (ge8 >= 782) return;
        xpart_body(X, Bf, C1, M, (ge8 >> 1) * 128, (ge8 & 1) * 8, smem);
    }
}

// ==== GEMM1: h[chunked] = relu(A @ Wp + b) (R7-proven gemm_k, OMODE=1 only) ====
__global__ __launch_bounds__(256) void gemm1_k(const u16* __restrict__ A1,
                                               const u16* __restrict__ Bf,
                                               const float* __restrict__ bias,
                                               u16* __restrict__ obf, int M) {
    __shared__ u16 sAB[2][8192];
    const int lane = threadIdx.x & 63;
    const int w = threadIdx.x >> 6;
    const int wm = w >> 1, wn = w & 1;
    const int row_base = blockIdx.x * 128;
    const int ct0b = blockIdx.y * 8;
    const int lr = lane & 15, lk = lane >> 4;

    f32x4 acc[4][4] = {};

    auto stage = [&](int buf, int kt) {
#pragma unroll
        for (int j = 0; j < 2; ++j) {
            int row = row_base + j * 64 + lane;
            if (row >= M) row = M - 1;
            gld16(&sAB[buf][(w * 2 + j) * 512 + lane * 8],
                  A1 + (size_t)row * DD + kt * 32 + w * 8);
        }
#pragma unroll
        for (int j = 0; j < 2; ++j) {
            const int nl = w * 2 + j;
            gld16(&sAB[buf][4096 + nl * 512 + lane * 8],
                  Bf + ((size_t)(kt * 16 + ct0b + nl) * 64 + lane) * 8);
        }
    };
    auto compute = [&](int buf) {
        bf16x8 a[4], b[4];
#pragma unroll
        for (int m = 0; m < 4; m++)
            a[m] = *reinterpret_cast<const bf16x8*>(
                &sAB[buf][lk * 1024 + (wm * 64 + m * 16 + lr) * 8]);
#pragma unroll
        for (int n = 0; n < 4; n++)
            b[n] = *reinterpret_cast<const bf16x8*>(
                &sAB[buf][4096 + (wn * 4 + n) * 512 + lane * 8]);
#pragma unroll
        for (int m = 0; m < 4; m++)
#pragma unroll
            for (int n = 0; n < 4; n++)
                acc[m][n] = __builtin_amdgcn_mfma_f32_16x16x32_bf16(a[m], b[n], acc[m][n], 0, 0, 0);
    };

    stage(0, 0);
    asm volatile("s_waitcnt vmcnt(0)" ::: "memory");
    __syncthreads();
    int buf = 0;
#pragma unroll
    for (int kt = 0; kt < 7; ++kt) {
        stage(buf ^ 1, kt + 1);
        compute(buf);
        asm volatile("s_waitcnt vmcnt(0)" ::: "memory");
        __syncthreads();
        buf ^= 1;
    }
    compute(buf);

    const int col_base = blockIdx.y * 128 + wn * 64;
#pragma unroll
    for (int n = 0; n < 4; n++) {
        const int col = col_base + n * 16 + lr;
        const float bz = bias[col];
#pragma unroll
        for (int m = 0; m < 4; m++) {
            const int r0 = row_base + wm * 64 + m * 16 + lk * 4;
#pragma unroll
            for (int e = 0; e < 4; e++) {
                const int r = r0 + e;
                if (r < M) {
                    float v = fmaxf(acc[m][n][e] + bz, 0.0f);
                    obf[((size_t)(col >> 5) * N_NODES + r) * 32 + (col & 31)] = f2bf(v);
                }
            }
        }
    }
}

// ==== GEMM2b: out = C1 + agg[chunked] @ Wfc_bot + bias ====
// FINAL=false: relu -> bf16 obf; FINAL=true: f32 of32 (may alias C1; same-thread RMW).
template <bool FINAL>
__global__ __launch_bounds__(256) void gemm2b_k(const u16* __restrict__ A2,
                                                const u16* __restrict__ Bf,
                                                const float* __restrict__ bias,
                                                const float* __restrict__ C1,
                                                u16* __restrict__ obf,
                                                float* __restrict__ of32, int M) {
    __shared__ u16 sAB[2][8192];
    const int lane = threadIdx.x & 63;
    const int w = threadIdx.x >> 6;
    const int wm = w >> 1, wn = w & 1;
    const int row_base = blockIdx.x * 128;
    const int ct0b = blockIdx.y * 8;
    const int lr = lane & 15, lk = lane >> 4;

    f32x4 acc[4][4] = {};

    auto stage = [&](int buf, int k) {  // k = 0..7 -> Wfc rows 256..511, agg chunk k
#pragma unroll
        for (int j = 0; j < 2; ++j) {
            int row = row_base + j * 64 + lane;
            if (row >= M) row = M - 1;
            gld16(&sAB[buf][(w * 2 + j) * 512 + lane * 8],
                  A2 + ((size_t)k * N_NODES + row) * 32 + w * 8);
        }
#pragma unroll
        for (int j = 0; j < 2; ++j) {
            const int nl = w * 2 + j;
            gld16(&sAB[buf][4096 + nl * 512 + lane * 8],
                  Bf + ((size_t)((8 + k) * 16 + ct0b + nl) * 64 + lane) * 8);
        }
    };
    auto compute = [&](int buf) {
        bf16x8 a[4], b[4];
#pragma unroll
        for (int m = 0; m < 4; m++)
            a[m] = *reinterpret_cast<const bf16x8*>(
                &sAB[buf][lk * 1024 + (wm * 64 + m * 16 + lr) * 8]);
#pragma unroll
        for (int n = 0; n < 4; n++)
            b[n] = *reinterpret_cast<const bf16x8*>(
                &sAB[buf][4096 + (wn * 4 + n) * 512 + lane * 8]);
#pragma unroll
        for (int m = 0; m < 4; m++)
#pragma unroll
            for (int n = 0; n < 4; n++)
                acc[m][n] = __builtin_amdgcn_mfma_f32_16x16x32_bf16(a[m], b[n], acc[m][n], 0, 0, 0);
    };

    stage(0, 0);
    asm volatile("s_waitcnt vmcnt(0)" ::: "memory");
    __syncthreads();
    int buf = 0;
#pragma unroll
    for (int k = 0; k < 7; ++k) {
        stage(buf ^ 1, k + 1);
        compute(buf);
        asm volatile("s_waitcnt vmcnt(0)" ::: "memory");
        __syncthreads();
        buf ^= 1;
    }
    compute(buf);

    const int col_base = blockIdx.y * 128 + wn * 64;
#pragma unroll
    for (int n = 0; n < 4; n++) {
        const int col = col_base + n * 16 + lr;
        const float bz = bias[col];
#pragma unroll
        for (int m = 0; m < 4; m++) {
            const int r0 = row_base + wm * 64 + m * 16 + lk * 4;
#pragma unroll
            for (int e = 0; e < 4; e++) {
                const int r = r0 + e;
                if (r < M) {
                    float v = acc[m][n][e] + bz + C1[(size_t)r * DD + col];
                    if (FINAL)
                        of32[(size_t)r * DD + col] = v;
                    else
                        obf[(size_t)r * DD + col] = f2bf(fmaxf(v, 0.0f));
                }
            }
        }
    }
}

extern "C" void kernel_launch(void* const* d_in, const int* in_sizes, int n_in,
                              void* d_out, int out_size, void* d_ws, size_t ws_size,
                              hipStream_t stream) {
    const float* features = (const float*)d_in[0];
    const int* neigh = (const int*)d_in[1];
    const float* Wp0 = (const float*)d_in[2];
    const float* bp0 = (const float*)d_in[3];
    const float* Wfc0 = (const float*)d_in[4];
    const float* bfc0 = (const float*)d_in[5];
    const float* Wp1 = (const float*)d_in[6];
    const float* bp1 = (const float*)d_in[7];
    const float* Wfc1 = (const float*)d_in[8];
    const float* bfc1 = (const float*)d_in[9];
    float* out = (float*)d_out;  // also used as f32 C1 scratch before final write

    const size_t ND = (size_t)N_NODES * DD;  // 12.8M
    u16* B0 = (u16*)d_ws;      // X bf16 -> later h1 (chunked)
    u16* B1 = B0 + ND;         // h0 (chunked) -> later O0 (row-major)
    u16* B2 = B1 + ND;         // agg (chunked)
    u16* Wpb0 = B2 + ND;
    u16* Wfb0 = Wpb0 + 65536;
    u16* Wpb1 = Wfb0 + 131072;
    u16* Wfb1 = Wpb1 + 65536;

    cvt_w_k<<<32, 256, 0, stream>>>(Wp0, Wpb0, 8);
    cvt_w_k<<<64, 256, 0, stream>>>(Wfc0, Wfb0, 16);
    cvt_w_k<<<32, 256, 0, stream>>>(Wp1, Wpb1, 8);
    cvt_w_k<<<64, 256, 0, stream>>>(Wfc1, Wfb1, 16);
    cvt_f32_bf16_k<<<12500, 256, 0, stream>>>((const float4*)features, B0);

    dim3 gg((N_NODES + 127) / 128, 2);  // 391 x 2
    const int gu = 294 * 8;             // union grid: 196 gather-groups + 98 gemm-groups

    // ---- layer 0 ----
    gemm1_k<<<gg, 256, 0, stream>>>(B0, Wpb0, bp0, B1, N_NODES);                 // h0 chunked
    union_k<<<gu, 256, 0, stream>>>(B0, B1, neigh, Wfb0, B2, out, N_NODES);      // gather0 || C1_0
    gemm2b_k<false><<<gg, 256, 0, stream>>>(B2, Wfb0, bfc0, out, B1, nullptr, N_NODES);  // O0 -> B1

    // ---- layer 1 ----
    gemm1_k<<<gg, 256, 0, stream>>>(B1, Wpb1, bp1, B0, N_NODES);                 // h1 chunked
    union_k<<<gu, 256, 0, stream>>>(B1, B0, neigh, Wfb1, B2, out, N_NODES);      // gather1 || C1_1
    gemm2b_k<true><<<gg, 256, 0, stream>>>(B2, Wfb1, bfc1, out, nullptr, out, N_NODES);  // final
}

// Round 9
// 228.663 us; speedup vs baseline: 1.5414x; 1.5414x over previous
//
#include <hip/hip_runtime.h>
#include <stdint.h>

#define N_NODES 50000
#define DD 256
#define SS 25

typedef unsigned short u16;
typedef __attribute__((ext_vector_type(8))) __bf16 bf16x8;
typedef __attribute__((ext_vector_type(4))) float f32x4;

__device__ __forceinline__ u16 f2bf(float f) {  // round-to-nearest-even
    union { float f; uint32_t i; } c;
    c.f = f;
    uint32_t r = c.i + 0x7fffu + ((c.i >> 16) & 1u);
    return (u16)(r >> 16);
}

// packed max of 2 non-negative bf16 (bit patterns monotone, sign bit 0 -> signed i16 max is exact)
__device__ __forceinline__ uint4 pkmax4(uint4 a, uint4 b) {
    uint4 d;
    asm("v_pk_max_i16 %0, %1, %2" : "=v"(d.x) : "v"(a.x), "v"(b.x));
    asm("v_pk_max_i16 %0, %1, %2" : "=v"(d.y) : "v"(a.y), "v"(b.y));
    asm("v_pk_max_i16 %0, %1, %2" : "=v"(d.z) : "v"(a.z), "v"(b.z));
    asm("v_pk_max_i16 %0, %1, %2" : "=v"(d.w) : "v"(a.w), "v"(b.w));
    return d;
}

__device__ __forceinline__ void gld16(void* lds, const void* g) {
    __builtin_amdgcn_global_load_lds(
        (const __attribute__((address_space(1))) uint32_t*)g,
        (__attribute__((address_space(3))) uint32_t*)lds, 16, 0, 0);
}

// ---- f32 -> bf16 elementwise (exact: grid*block*4 == n) ----
__global__ __launch_bounds__(256) void cvt_f32_bf16_k(const float4* __restrict__ in,
                                                      u16* __restrict__ out) {
    int i = blockIdx.x * 256 + threadIdx.x;
    float4 v = in[i];
    uint2 o;
    o.x = (uint32_t)f2bf(v.x) | ((uint32_t)f2bf(v.y) << 16);
    o.y = (uint32_t)f2bf(v.z) | ((uint32_t)f2bf(v.w) << 16);
    *reinterpret_cast<uint2*>(out + (size_t)i * 4) = o;
}

// ---- weight f32 [K][256] -> bf16 MFMA B-fragment layout ----
// out[((kt*16 + ct)*64 + lane)*8 + e] = W[kt*32 + (lane>>4)*8 + e][ct*16 + (lane&15)]
__global__ __launch_bounds__(256) void cvt_w_k(const float* __restrict__ W,
                                               u16* __restrict__ out, int KT) {
    int t = blockIdx.x * 256 + threadIdx.x;
    if (t >= KT * 16 * 64) return;
    int lane = t & 63;
    int ct = (t >> 6) & 15;
    int kt = t >> 10;
    int k0 = kt * 32 + (lane >> 4) * 8;
    int col = ct * 16 + (lane & 15);
    u16 r[8];
#pragma unroll
    for (int e = 0; e < 8; e++) r[e] = f2bf(W[(size_t)(k0 + e) * DD + col]);
    uint4 v;
    v.x = (uint32_t)r[0] | ((uint32_t)r[1] << 16);
    v.y = (uint32_t)r[2] | ((uint32_t)r[3] << 16);
    v.z = (uint32_t)r[4] | ((uint32_t)r[5] << 16);
    v.w = (uint32_t)r[6] | ((uint32_t)r[7] << 16);
    *reinterpret_cast<uint4*>(out + (size_t)t * 8) = v;
}

// ---- XCD-sliced gather + max-pool (R7-proven, unchanged) ----
__global__ __launch_bounds__(256) void gather_xcd_k(const u16* __restrict__ hc,
                                                    const int* __restrict__ idx,
                                                    u16* __restrict__ aggc, int M) {
    const int c = blockIdx.x & 7;
    const int base = (blockIdx.x >> 3) * 256;
    __shared__ int soff[256 * SS];
    const int tid = threadIdx.x;
    for (int j = tid; j < 256 * SS; j += 256) {
        int n = base + j / SS;
        if (n >= M) n = M - 1;
        soff[j] = idx[(size_t)n * SS + (j % SS)] * 32;
    }
    __syncthreads();
    const int q = tid & 3;
    const u16* slice = hc + (size_t)c * ((size_t)N_NODES * 32) + q * 8;
    u16* aslice = aggc + (size_t)c * ((size_t)N_NODES * 32) + q * 8;
#pragma unroll 1
    for (int p = 0; p < 4; ++p) {
        const int slot = p * 64 + (tid >> 2);
        const int n = base + slot;
        const int* off = &soff[slot * SS];
        uint4 v[13];
#pragma unroll
        for (int s = 0; s < 13; ++s)
            v[s] = *reinterpret_cast<const uint4*>(slice + off[s]);
        uint4 run = v[0];
#pragma unroll
        for (int s = 1; s < 13; ++s) run = pkmax4(run, v[s]);
#pragma unroll
        for (int s = 13; s < 25; ++s)
            v[s - 13] = *reinterpret_cast<const uint4*>(slice + off[s]);
#pragma unroll
        for (int s = 0; s < 12; ++s) run = pkmax4(run, v[s]);
        if (n < M)
            *reinterpret_cast<uint4*>(aslice + (size_t)n * 32) = run;
    }
}

// ---- bf16 MFMA GEMM, 128x256 tile, 8 waves, 3-stage counted-vmcnt pipeline ----
// out[M,256] = [A1 | A2][M, 32*KT] @ Bf + bias.
// A1 row-major [N][256]; A2 (agg) chunked [8][N][32].
// OMODE: 0 = bf16 row-major (+relu opt), 1 = bf16 chunked [8][N][32], 2 = f32 row-major.
template <int KT, bool RELU, int OMODE>
__global__ __launch_bounds__(512, 4) void gemm_k(const u16* __restrict__ A1,
                                                 const u16* __restrict__ A2,
                                                 const u16* __restrict__ Bf,
                                                 const float* __restrict__ bias,
                                                 u16* __restrict__ obf,
                                                 float* __restrict__ of32, int M) {
    __shared__ u16 sA[3][4096];  // [lk 0..3][128 rows][8], 8KB per buf
    __shared__ u16 sB[3][8192];  // 16 frags x 64 lanes x 8, 16KB per buf
    const int tid = threadIdx.x;
    const int lane = tid & 63, w = tid >> 6;
    const int wm = w >> 2, wn = w & 3;  // 2x4 wave grid: 64 rows x 64 cols each
    const int row_base = blockIdx.x * 128;
    const int lr = lane & 15, lk = lane >> 4;
    const int arow = tid & 127, alk = tid >> 7;  // staging map for A

    auto stage = [&](int buf, int kt) {
        int row = row_base + arow;
        if (row >= M) row = M - 1;
        const u16* srcA = (KT == 16 && kt >= 8)
                              ? A2 + ((size_t)(kt & 7) * N_NODES + row) * 32 + alk * 8
                              : A1 + (size_t)row * DD + (kt & 7) * 32 + alk * 8;
        gld16(&sA[buf][tid * 8], srcA);  // 1 load
#pragma unroll
        for (int j = 0; j < 2; ++j) {   // 2 loads
            const int idx = tid + j * 512;
            const int nl = idx >> 6, li = idx & 63;
            gld16(&sB[buf][idx * 8], Bf + ((size_t)(kt * 16 + nl) * 64 + li) * 8);
        }
    };  // exactly 3 vmcnt ops per thread per stage

    f32x4 acc[4][4] = {};
    auto compute = [&](int buf) {
        bf16x8 a[4], b[4];
#pragma unroll
        for (int m = 0; m < 4; m++)
            a[m] = *reinterpret_cast<const bf16x8*>(
                &sA[buf][(lk * 128 + wm * 64 + m * 16 + lr) * 8]);
#pragma unroll
        for (int n = 0; n < 4; n++)
            b[n] = *reinterpret_cast<const bf16x8*>(
                &sB[buf][((wn * 4 + n) * 64 + lane) * 8]);
#pragma unroll
        for (int m = 0; m < 4; m++)
#pragma unroll
            for (int n = 0; n < 4; n++)
                acc[m][n] = __builtin_amdgcn_mfma_f32_16x16x32_bf16(a[m], b[n], acc[m][n], 0, 0, 0);
    };

    stage(0, 0);
    stage(1, 1);
#pragma unroll
    for (int kt = 0; kt < KT; ++kt) {
        if (kt + 1 < KT)
            asm volatile("s_waitcnt vmcnt(3)" ::: "memory");  // stage kt landed, kt+1 in flight
        else
            asm volatile("s_waitcnt vmcnt(0)" ::: "memory");
        __builtin_amdgcn_s_barrier();
        if (kt + 2 < KT) stage((kt + 2) % 3, kt + 2);
        compute(kt % 3);
    }

    // epilogue: wave (wm,wn) owns rows [wm*64,+64) x cols [wn*64,+64)
#pragma unroll
    for (int n = 0; n < 4; n++) {
        const int col = wn * 64 + n * 16 + lr;
        const float bz = bias[col];
#pragma unroll
        for (int m = 0; m < 4; m++) {
            const int r0 = row_base + wm * 64 + m * 16 + lk * 4;
#pragma unroll
            for (int e = 0; e < 4; e++) {
                const int r = r0 + e;
                if (r < M) {
                    float v = acc[m][n][e] + bz;
                    if (RELU) v = fmaxf(v, 0.0f);
                    if (OMODE == 0)
                        obf[(size_t)r * DD + col] = f2bf(v);
                    else if (OMODE == 1)  // chunked: [col>>5][r][col&31]
                        obf[((size_t)(col >> 5) * N_NODES + r) * 32 + (col & 31)] = f2bf(v);
                    else
                        of32[(size_t)r * DD + col] = v;
                }
            }
        }
    }
}

extern "C" void kernel_launch(void* const* d_in, const int* in_sizes, int n_in,
                              void* d_out, int out_size, void* d_ws, size_t ws_size,
                              hipStream_t stream) {
    const float* features = (const float*)d_in[0];
    const int* neigh = (const int*)d_in[1];
    const float* Wp0 = (const float*)d_in[2];
    const float* bp0 = (const float*)d_in[3];
    const float* Wfc0 = (const float*)d_in[4];
    const float* bfc0 = (const float*)d_in[5];
    const float* Wp1 = (const float*)d_in[6];
    const float* bp1 = (const float*)d_in[7];
    const float* Wfc1 = (const float*)d_in[8];
    const float* bfc1 = (const float*)d_in[9];
    float* out = (float*)d_out;

    const size_t ND = (size_t)N_NODES * DD;  // 12.8M
    u16* B0 = (u16*)d_ws;      // X bf16 -> later h1 (chunked)
    u16* B1 = B0 + ND;         // h0 (chunked) -> later O0 (row-major)
    u16* B2 = B1 + ND;         // agg (chunked)
    u16* Wpb0 = B2 + ND;
    u16* Wfb0 = Wpb0 + 65536;
    u16* Wpb1 = Wfb0 + 131072;
    u16* Wfb1 = Wpb1 + 65536;

    cvt_w_k<<<32, 256, 0, stream>>>(Wp0, Wpb0, 8);
    cvt_w_k<<<64, 256, 0, stream>>>(Wfc0, Wfb0, 16);
    cvt_w_k<<<32, 256, 0, stream>>>(Wp1, Wpb1, 8);
    cvt_w_k<<<64, 256, 0, stream>>>(Wfc1, Wfb1, 16);
    cvt_f32_bf16_k<<<12500, 256, 0, stream>>>((const float4*)features, B0);

    const int gg = (N_NODES + 127) / 128;        // 391
    const int gx = ((N_NODES + 255) / 256) * 8;  // 1568

    // ---- layer 0 ----
    gemm_k<8, true, 1><<<gg, 512, 0, stream>>>(B0, nullptr, Wpb0, bp0, B1, nullptr, N_NODES);
    gather_xcd_k<<<gx, 256, 0, stream>>>(B1, neigh, B2, N_NODES);
    gemm_k<16, true, 0><<<gg, 512, 0, stream>>>(B0, B2, Wfb0, bfc0, B1, nullptr, N_NODES);

    // ---- layer 1 ---- (B0 dead -> h1 chunked; B1 holds O0)
    gemm_k<8, true, 1><<<gg, 512, 0, stream>>>(B1, nullptr, Wpb1, bp1, B0, nullptr, N_NODES);
    gather_xcd_k<<<gx, 256, 0, stream>>>(B0, neigh, B2, N_NODES);
    gemm_k<16, false, 2><<<gg, 512, 0, stream>>>(B1, B2, Wfb1, bfc1, nullptr, out, N_NODES);
}

// Round 10
// 221.862 us; speedup vs baseline: 1.5886x; 1.0307x over previous
//
#include <hip/hip_runtime.h>
#include <stdint.h>

#define N_NODES 50000
#define DD 256
#define SS 25

typedef unsigned short u16;
typedef __attribute__((ext_vector_type(8))) __bf16 bf16x8;
typedef __attribute__((ext_vector_type(4))) float f32x4;

__device__ __forceinline__ u16 f2bf(float f) {  // round-to-nearest-even
    union { float f; uint32_t i; } c;
    c.f = f;
    uint32_t r = c.i + 0x7fffu + ((c.i >> 16) & 1u);
    return (u16)(r >> 16);
}

// packed max of 2 non-negative bf16 (bit patterns monotone, sign bit 0 -> signed i16 max is exact)
__device__ __forceinline__ uint4 pkmax4(uint4 a, uint4 b) {
    uint4 d;
    asm("v_pk_max_i16 %0, %1, %2" : "=v"(d.x) : "v"(a.x), "v"(b.x));
    asm("v_pk_max_i16 %0, %1, %2" : "=v"(d.y) : "v"(a.y), "v"(b.y));
    asm("v_pk_max_i16 %0, %1, %2" : "=v"(d.z) : "v"(a.z), "v"(b.z));
    asm("v_pk_max_i16 %0, %1, %2" : "=v"(d.w) : "v"(a.w), "v"(b.w));
    return d;
}

__device__ __forceinline__ void gld16(void* lds, const void* g) {
    __builtin_amdgcn_global_load_lds(
        (const __attribute__((address_space(1))) uint32_t*)g,
        (__attribute__((address_space(3))) uint32_t*)lds, 16, 0, 0);
}

// ---- f32 -> bf16 elementwise (exact: grid*block*4 == n) ----
__global__ __launch_bounds__(256) void cvt_f32_bf16_k(const float4* __restrict__ in,
                                                      u16* __restrict__ out) {
    int i = blockIdx.x * 256 + threadIdx.x;
    float4 v = in[i];
    uint2 o;
    o.x = (uint32_t)f2bf(v.x) | ((uint32_t)f2bf(v.y) << 16);
    o.y = (uint32_t)f2bf(v.z) | ((uint32_t)f2bf(v.w) << 16);
    *reinterpret_cast<uint2*>(out + (size_t)i * 4) = o;
}

// ---- weight f32 [K][256] -> bf16 MFMA B-fragment layout ----
// out[((kt*16 + ct)*64 + lane)*8 + e] = W[kt*32 + (lane>>4)*8 + e][ct*16 + (lane&15)]
__global__ __launch_bounds__(256) void cvt_w_k(const float* __restrict__ W,
                                               u16* __restrict__ out, int KT) {
    int t = blockIdx.x * 256 + threadIdx.x;
    if (t >= KT * 16 * 64) return;
    int lane = t & 63;
    int ct = (t >> 6) & 15;
    int kt = t >> 10;
    int k0 = kt * 32 + (lane >> 4) * 8;
    int col = ct * 16 + (lane & 15);
    u16 r[8];
#pragma unroll
    for (int e = 0; e < 8; e++) r[e] = f2bf(W[(size_t)(k0 + e) * DD + col]);
    uint4 v;
    v.x = (uint32_t)r[0] | ((uint32_t)r[1] << 16);
    v.y = (uint32_t)r[2] | ((uint32_t)r[3] << 16);
    v.z = (uint32_t)r[4] | ((uint32_t)r[5] << 16);
    v.w = (uint32_t)r[6] | ((uint32_t)r[7] << 16);
    *reinterpret_cast<uint4*>(out + (size_t)t * 8) = v;
}

// ---- XCD-sliced gather + max-pool (R7-proven, unchanged) ----
__global__ __launch_bounds__(256) void gather_xcd_k(const u16* __restrict__ hc,
                                                    const int* __restrict__ idx,
                                                    u16* __restrict__ aggc, int M) {
    const int c = blockIdx.x & 7;
    const int base = (blockIdx.x >> 3) * 256;
    __shared__ int soff[256 * SS];
    const int tid = threadIdx.x;
    for (int j = tid; j < 256 * SS; j += 256) {
        int n = base + j / SS;
        if (n >= M) n = M - 1;
        soff[j] = idx[(size_t)n * SS + (j % SS)] * 32;
    }
    __syncthreads();
    const int q = tid & 3;
    const u16* slice = hc + (size_t)c * ((size_t)N_NODES * 32) + q * 8;
    u16* aslice = aggc + (size_t)c * ((size_t)N_NODES * 32) + q * 8;
#pragma unroll 1
    for (int p = 0; p < 4; ++p) {
        const int slot = p * 64 + (tid >> 2);
        const int n = base + slot;
        const int* off = &soff[slot * SS];
        uint4 v[13];
#pragma unroll
        for (int s = 0; s < 13; ++s)
            v[s] = *reinterpret_cast<const uint4*>(slice + off[s]);
        uint4 run = v[0];
#pragma unroll
        for (int s = 1; s < 13; ++s) run = pkmax4(run, v[s]);
#pragma unroll
        for (int s = 13; s < 25; ++s)
            v[s - 13] = *reinterpret_cast<const uint4*>(slice + off[s]);
#pragma unroll
        for (int s = 0; s < 12; ++s) run = pkmax4(run, v[s]);
        if (n < M)
            *reinterpret_cast<uint4*>(aslice + (size_t)n * 32) = run;
    }
}

// ---- bf16 MFMA GEMM, 128x256 tile, 8 waves, 4A/3B-stage counted-vmcnt pipeline ----
// out[M,256] = [A1 | A2][M, 32*KT] @ Bf + bias.
// A1 row-major [N][256]; A2 (agg) chunked [8][N][32].
// A staged coalesced (quad-per-row) into row-major-64B LDS with XOR slot swizzle
// slot = kc ^ swz(row), swz(r) = (r + (r>>2)) & 3  -> staging 16 lines/wave,
// fragment ds_read_b128 exactly 2 addrs/bank (free). Issue order B(kt+2), A(kt+3):
// FIFO gives steady vmcnt(4); A ~2.5 iters in flight (HBM), B ~1.5 (L2-hot).
// OMODE: 0 = bf16 row-major (+relu opt), 1 = bf16 chunked [8][N][32], 2 = f32 row-major.
template <int KT, bool RELU, int OMODE>
__global__ __launch_bounds__(512, 4) void gemm_k(const u16* __restrict__ A1,
                                                 const u16* __restrict__ A2,
                                                 const u16* __restrict__ Bf,
                                                 const float* __restrict__ bias,
                                                 u16* __restrict__ obf,
                                                 float* __restrict__ of32, int M) {
    __shared__ u16 sA[4][4096];  // [row 0..127][slot 0..3][8], 8KB per buf
    __shared__ u16 sB[3][8192];  // 16 frags x 64 lanes x 8, 16KB per buf
    const int tid = threadIdx.x;
    const int lane = tid & 63, w = tid >> 6;
    const int wm = w >> 2, wn = w & 3;  // 2x4 wave grid: 64 rows x 64 cols each
    const int row_base = blockIdx.x * 128;
    const int lr = lane & 15, lk = lane >> 4;

    // staging map: arow = tid>>2 (16 full 64B rows per wave), slot = tid&3
    const int arow = tid >> 2;
    const int swzr = (arow + (arow >> 2)) & 3;
    const int kc = (tid & 3) ^ swzr;  // semantic k-chunk stored at this slot
    int sgrow = row_base + arow;
    if (sgrow >= M) sgrow = M - 1;

    auto stageB = [&](int buf, int kt) {
#pragma unroll
        for (int j = 0; j < 2; ++j) {
            const int idx = tid + j * 512;
            const int nl = idx >> 6, li = idx & 63;
            gld16(&sB[buf][idx * 8], Bf + ((size_t)(kt * 16 + nl) * 64 + li) * 8);
        }
    };
    auto stageA = [&](int buf, int kt) {
        const u16* srcA = (KT == 16 && kt >= 8)
                              ? A2 + ((size_t)(kt & 7) * N_NODES + sgrow) * 32 + kc * 8
                              : A1 + (size_t)sgrow * DD + (kt & 7) * 32 + kc * 8;
        gld16(&sA[buf][tid * 8], srcA);
    };

    f32x4 acc[4][4] = {};
    const int swzl = (lr + (lr >> 2)) & 3;  // swz(row) is wm/m-independent
    auto compute = [&](int bufA, int bufB) {
        bf16x8 a[4], b[4];
#pragma unroll
        for (int m = 0; m < 4; m++) {
            const int row = wm * 64 + m * 16 + lr;
            a[m] = *reinterpret_cast<const bf16x8*>(
                &sA[bufA][(row * 4 + (lk ^ swzl)) * 8]);
        }
#pragma unroll
        for (int n = 0; n < 4; n++)
            b[n] = *reinterpret_cast<const bf16x8*>(
                &sB[bufB][((wn * 4 + n) * 64 + lane) * 8]);
#pragma unroll
        for (int m = 0; m < 4; m++)
#pragma unroll
            for (int n = 0; n < 4; n++)
                acc[m][n] = __builtin_amdgcn_mfma_f32_16x16x32_bf16(a[m], b[n], acc[m][n], 0, 0, 0);
    };

    // prologue FIFO: B0,B0,A0,B1,B1,A1,A2  (7 outstanding)
    stageB(0, 0);
    stageA(0, 0);
    stageB(1, 1);
    stageA(1, 1);
    stageA(2, 2);
#pragma unroll
    for (int kt = 0; kt < KT; ++kt) {
        if (kt < KT - 2)
            asm volatile("s_waitcnt vmcnt(4)" ::: "memory");
        else if (kt == KT - 2)
            asm volatile("s_waitcnt vmcnt(3)" ::: "memory");
        else
            asm volatile("s_waitcnt vmcnt(0)" ::: "memory");
        __builtin_amdgcn_s_barrier();
        if (kt + 2 < KT) stageB((kt + 2) % 3, kt + 2);
        if (kt + 3 < KT) stageA((kt + 3) & 3, kt + 3);
        compute(kt & 3, kt % 3);
    }

    // epilogue: wave (wm,wn) owns rows [wm*64,+64) x cols [wn*64,+64)
#pragma unroll
    for (int n = 0; n < 4; n++) {
        const int col = wn * 64 + n * 16 + lr;
        const float bz = bias[col];
#pragma unroll
        for (int m = 0; m < 4; m++) {
            const int r0 = row_base + wm * 64 + m * 16 + lk * 4;
#pragma unroll
            for (int e = 0; e < 4; e++) {
                const int r = r0 + e;
                if (r < M) {
                    float v = acc[m][n][e] + bz;
                    if (RELU) v = fmaxf(v, 0.0f);
                    if (OMODE == 0)
                        obf[(size_t)r * DD + col] = f2bf(v);
                    else if (OMODE == 1)  // chunked: [col>>5][r][col&31]
                        obf[((size_t)(col >> 5) * N_NODES + r) * 32 + (col & 31)] = f2bf(v);
                    else
                        of32[(size_t)r * DD + col] = v;
                }
            }
        }
    }
}

extern "C" void kernel_launch(void* const* d_in, const int* in_sizes, int n_in,
                              void* d_out, int out_size, void* d_ws, size_t ws_size,
                              hipStream_t stream) {
    const float* features = (const float*)d_in[0];
    const int* neigh = (const int*)d_in[1];
    const float* Wp0 = (const float*)d_in[2];
    const float* bp0 = (const float*)d_in[3];
    const float* Wfc0 = (const float*)d_in[4];
    const float* bfc0 = (const float*)d_in[5];
    const float* Wp1 = (const float*)d_in[6];
    const float* bp1 = (const float*)d_in[7];
    const float* Wfc1 = (const float*)d_in[8];
    const float* bfc1 = (const float*)d_in[9];
    float* out = (float*)d_out;

    const size_t ND = (size_t)N_NODES * DD;  // 12.8M
    u16* B0 = (u16*)d_ws;      // X bf16 -> later h1 (chunked)
    u16* B1 = B0 + ND;         // h0 (chunked) -> later O0 (row-major)
    u16* B2 = B1 + ND;         // agg (chunked)
    u16* Wpb0 = B2 + ND;
    u16* Wfb0 = Wpb0 + 65536;
    u16* Wpb1 = Wfb0 + 131072;
    u16* Wfb1 = Wpb1 + 65536;

    cvt_w_k<<<32, 256, 0, stream>>>(Wp0, Wpb0, 8);
    cvt_w_k<<<64, 256, 0, stream>>>(Wfc0, Wfb0, 16);
    cvt_w_k<<<32, 256, 0, stream>>>(Wp1, Wpb1, 8);
    cvt_w_k<<<64, 256, 0, stream>>>(Wfc1, Wfb1, 16);
    cvt_f32_bf16_k<<<12500, 256, 0, stream>>>((const float4*)features, B0);

    const int gg = (N_NODES + 127) / 128;        // 391
    const int gx = ((N_NODES + 255) / 256) * 8;  // 1568

    // ---- layer 0 ----
    gemm_k<8, true, 1><<<gg, 512, 0, stream>>>(B0, nullptr, Wpb0, bp0, B1, nullptr, N_NODES);
    gather_xcd_k<<<gx, 256, 0, stream>>>(B1, neigh, B2, N_NODES);
    gemm_k<16, true, 0><<<gg, 512, 0, stream>>>(B0, B2, Wfb0, bfc0, B1, nullptr, N_NODES);

    // ---- layer 1 ---- (B0 dead -> h1 chunked; B1 holds O0)
    gemm_k<8, true, 1><<<gg, 512, 0, stream>>>(B1, nullptr, Wpb1, bp1, B0, nullptr, N_NODES);
    gather_xcd_k<<<gx, 256, 0, stream>>>(B0, neigh, B2, N_NODES);
    gemm_k<16, false, 2><<<gg, 512, 0, stream>>>(B1, B2, Wfb1, bfc1, nullptr, out, N_NODES);
}